// Round 1
// baseline (593.097 us; speedup 1.0000x reference)
//
#include <hip/hip_runtime.h>

// Problem constants: EMB=64, HEADS=8, TOK=10, CAP=32 (tables 63 rows),
// dim_q=dim_k=4116, dim_i=20, dim_h=dim_w=dim_d=16. S=4096; dim_q=20+4096.
//
// Output (flat fp32): out[h][q][k], h<8, q<4116, k<4116.
//   q <  20            : zeros
//   q >= 20, k <  20   : cross_s[h][k]            * 0.125
//   q >= 20, k >= 20   : (row_s[h][i][l] + col_s[h][j][m] + dep_s[h][kk][n]) * 0.125/3
//     r=q-20: i=r>>8, j=(r>>4)&15, kk=r&15;  c=k-20: l=c>>8, m=(c>>4)&15, n=c&15
//
// ws layout (floats): [0..159]     cross_s (8x20, pre-scaled by 0.125)
//                     [160..2207]  row_s  (8x16x16, pre-scaled by 0.125/3)
//                     [2208..4255] col_s
//                     [4256..6303] dep_s

#define EMB 64
#define NHEADS 8
#define DIM_I 20
#define DIM_Q 4116
#define NCHUNK 1029   // DIM_Q/4 float4 per row (row = 16464 B, 16B aligned)

__global__ __launch_bounds__(256) void tables_kernel(
    const float* __restrict__ enc_cross,  // [2][10][64] -> flat [20][64]
    const float* __restrict__ enc_h,      // [63][64]
    const float* __restrict__ enc_w,
    const float* __restrict__ enc_d,
    const float* __restrict__ w_cross,    // [8][64]
    const float* __restrict__ w_h,
    const float* __restrict__ w_w,
    const float* __restrict__ w_d,
    float* __restrict__ tabs)
{
    const int tid = blockIdx.x * blockDim.x + threadIdx.x;
    const int total = NHEADS * DIM_I + 3 * NHEADS * 256;  // 160 + 6144 = 6304
    if (tid >= total) return;

    if (tid < NHEADS * DIM_I) {
        const int h = tid / DIM_I;
        const int n = tid % DIM_I;
        const float* wv = w_cross + h * EMB;
        const float* ev = enc_cross + n * EMB;
        float acc = 0.f;
        #pragma unroll
        for (int c = 0; c < EMB; ++c) acc += wv[c] * ev[c];
        tabs[tid] = acc * 0.125f;
    } else {
        const int u = tid - NHEADS * DIM_I;
        const int table = u >> 11;          // 0=row, 1=col, 2=dep (2048 each)
        const int v = u & 2047;
        const int h = v >> 8;
        const int i = (v >> 4) & 15;
        const int l = v & 15;
        const int ridx = l - i + 31;        // always in [16,46], no clipping needed
        const float* wv;
        const float* ev;
        if (table == 0)      { wv = w_h + h * EMB; ev = enc_h + ridx * EMB; }
        else if (table == 1) { wv = w_w + h * EMB; ev = enc_w + ridx * EMB; }
        else                 { wv = w_d + h * EMB; ev = enc_d + ridx * EMB; }
        float acc = 0.f;
        #pragma unroll
        for (int c = 0; c < EMB; ++c) acc += wv[c] * ev[c];
        tabs[tid] = acc * (0.125f / 3.0f);
    }
}

// One block per (h,i,j): writes 16 consecutive rows (kk=0..15) = 263 KB
// contiguous. Tables staged in LDS; rs[l]+cs[m] precomputed per block.
// Grid: 2048 content blocks + 64 zero blocks (8 per head).
__global__ __launch_bounds__(256) void fill_kernel(
    const float* __restrict__ tabs, float* __restrict__ out)
{
    const int tid = threadIdx.x;
    const int bid = blockIdx.x;

    if (bid >= 2048) {
        // zero rows q<20: 8 blocks per head, contiguous 20*1029 float4 region
        const int z = bid - 2048;
        const int h = z >> 3;
        const int part = z & 7;
        float4* zp = (float4*)(out + (size_t)h * DIM_Q * DIM_Q);
        const int ztotal = DIM_I * NCHUNK;      // 20580 float4
        const int per = (ztotal + 7) / 8;       // 2573
        const int lo = part * per;
        const int hi = min(ztotal, lo + per);
        const float4 zv = make_float4(0.f, 0.f, 0.f, 0.f);
        for (int v = lo + tid; v < hi; v += 256) zp[v] = zv;
        return;
    }

    const int h   = bid >> 8;       // 0..7
    const int rem = bid & 255;
    const int i   = rem >> 4;       // 0..15
    const int j   = rem & 15;       // 0..15

    __shared__ __align__(16) float s_dep[256];   // dep_s[h][16][16]
    __shared__ float s_cross[20];
    __shared__ float s_rs[16];
    __shared__ float s_cs[16];
    __shared__ float s_blm[256];                 // rs[l]+cs[m], idx = l*16+m

    s_dep[tid] = tabs[160 + 4096 + h * 256 + tid];
    if (tid < 20)                 s_cross[tid]    = tabs[h * DIM_I + tid];
    if (tid >= 32 && tid < 48)    s_rs[tid - 32]  = tabs[160 + h * 256 + i * 16 + (tid - 32)];
    if (tid >= 64 && tid < 80)    s_cs[tid - 64]  = tabs[160 + 2048 + h * 256 + j * 16 + (tid - 64)];
    __syncthreads();
    s_blm[tid] = s_rs[tid >> 4] + s_cs[tid & 15];
    __syncthreads();

    const int q0 = DIM_I + i * 256 + j * 16;     // first of 16 consecutive rows
    float4* p = (float4*)(out + ((size_t)h * DIM_Q + q0) * DIM_Q);

    for (int t = tid; t < NCHUNK; t += 256) {
        float4* pt = p + t;
        if (t < 5) {
            // k = 4t..4t+3 < 20: cross block, same value for all 16 rows
            const int k0 = 4 * t;
            const float4 v = make_float4(s_cross[k0], s_cross[k0 + 1],
                                         s_cross[k0 + 2], s_cross[k0 + 3]);
            #pragma unroll
            for (int kk = 0; kk < 16; ++kk) pt[kk * NCHUNK] = v;
        } else {
            const int c0 = 4 * t - DIM_I;        // multiple of 4, 0..4092
            const float blm = s_blm[c0 >> 4];    // rs[l]+cs[m]
            const int n0 = c0 & 15;              // {0,4,8,12}
            #pragma unroll
            for (int kk = 0; kk < 16; ++kk) {
                const float4 d = *(const float4*)&s_dep[kk * 16 + n0];
                pt[kk * NCHUNK] = make_float4(blm + d.x, blm + d.y,
                                              blm + d.z, blm + d.w);
            }
        }
    }
}

extern "C" void kernel_launch(void* const* d_in, const int* in_sizes, int n_in,
                              void* d_out, int out_size, void* d_ws, size_t ws_size,
                              hipStream_t stream)
{
    const float* enc_cross = (const float*)d_in[0];
    const float* enc_h     = (const float*)d_in[1];
    const float* enc_w     = (const float*)d_in[2];
    const float* enc_d     = (const float*)d_in[3];
    const float* w_cross   = (const float*)d_in[4];
    const float* w_h       = (const float*)d_in[5];
    const float* w_w       = (const float*)d_in[6];
    const float* w_d       = (const float*)d_in[7];

    float* tabs = (float*)d_ws;   // 6304 floats = 25,216 B

    tables_kernel<<<dim3(25), dim3(256), 0, stream>>>(
        enc_cross, enc_h, enc_w, enc_d, w_cross, w_h, w_w, w_d, tabs);

    fill_kernel<<<dim3(2048 + 64), dim3(256), 0, stream>>>(
        tabs, (float*)d_out);
}

// Round 2
// 590.280 us; speedup vs baseline: 1.0048x; 1.0048x over previous
//
#include <hip/hip_runtime.h>

// Problem constants: EMB=64, HEADS=8, TOK=10, CAP=32 (tables 63 rows),
// dim_q=dim_k=4116, dim_i=20, dim_h=dim_w=dim_d=16. S=4096; dim_q=20+4096.
//
// Output (flat fp32): out[h][q][k], h<8, q<4116, k<4116.
//   q <  20            : zeros
//   q >= 20, k <  20   : cross_s[h][k]            * 0.125
//   q >= 20, k >= 20   : (row_s[h][i][l] + col_s[h][j][m] + dep_s[h][kk][n]) * 0.125/3
//     r=q-20: i=r>>8, j=(r>>4)&15, kk=r&15;  c=k-20: l=c>>8, m=(c>>4)&15, n=c&15
//
// ws layout (floats): [0..159]     cross_s (8x20, pre-scaled by 0.125)
//                     [160..2207]  row_s  (8x16x16, pre-scaled by 0.125/3)
//                     [2208..4255] col_s
//                     [4256..6303] dep_s
//
// R2 change vs R0 baseline: nontemporal stores on all output writes
// (write-once 542 MB stream; avoid L2 dirty-allocate path), float4 table
// reads. Structure otherwise identical to the 568 µs R0 kernel.

#define EMB 64
#define NHEADS 8
#define DIM_I 20
#define DIM_Q 4116
#define NCHUNK 1029   // DIM_Q/4 float4 per row (row = 16464 B, 16B aligned)

typedef float f32x4 __attribute__((ext_vector_type(4)));

__global__ __launch_bounds__(256) void tables_kernel(
    const float* __restrict__ enc_cross,  // [2][10][64] -> flat [20][64]
    const float* __restrict__ enc_h,      // [63][64]
    const float* __restrict__ enc_w,
    const float* __restrict__ enc_d,
    const float* __restrict__ w_cross,    // [8][64]
    const float* __restrict__ w_h,
    const float* __restrict__ w_w,
    const float* __restrict__ w_d,
    float* __restrict__ tabs)
{
    const int tid = blockIdx.x * blockDim.x + threadIdx.x;
    const int total = NHEADS * DIM_I + 3 * NHEADS * 256;  // 160 + 6144 = 6304
    if (tid >= total) return;

    if (tid < NHEADS * DIM_I) {
        const int h = tid / DIM_I;
        const int n = tid % DIM_I;
        const float* wv = w_cross + h * EMB;
        const float* ev = enc_cross + n * EMB;
        float acc = 0.f;
        #pragma unroll
        for (int c = 0; c < EMB; ++c) acc += wv[c] * ev[c];
        tabs[tid] = acc * 0.125f;
    } else {
        const int u = tid - NHEADS * DIM_I;
        const int table = u >> 11;          // 0=row, 1=col, 2=dep (2048 each)
        const int v = u & 2047;
        const int h = v >> 8;
        const int i = (v >> 4) & 15;
        const int l = v & 15;
        const int ridx = l - i + 31;        // always in [16,46], no clipping needed
        const float* wv;
        const float* ev;
        if (table == 0)      { wv = w_h + h * EMB; ev = enc_h + ridx * EMB; }
        else if (table == 1) { wv = w_w + h * EMB; ev = enc_w + ridx * EMB; }
        else                 { wv = w_d + h * EMB; ev = enc_d + ridx * EMB; }
        float acc = 0.f;
        #pragma unroll
        for (int c = 0; c < EMB; ++c) acc += wv[c] * ev[c];
        tabs[tid] = acc * (0.125f / 3.0f);
    }
}

__global__ __launch_bounds__(256) void fill_kernel(
    const float* __restrict__ tabs, float* __restrict__ out)
{
    const int q = blockIdx.x;   // 0..4115
    const int h = blockIdx.y;   // 0..7

    f32x4* rowp = (f32x4*)(out + ((size_t)h * DIM_Q + q) * DIM_Q);

    if (q < DIM_I) {
        const f32x4 z = (f32x4)0.f;
        for (int t = threadIdx.x; t < NCHUNK; t += 256)
            __builtin_nontemporal_store(z, rowp + t);
        return;
    }

    const float* cross  = tabs + h * DIM_I;                  // [20]
    const float* row_s  = tabs + 160 + h * 256;              // [16][16]
    const float* col_s  = tabs + 160 + 2048 + h * 256;
    const float* dep_s  = tabs + 160 + 4096 + h * 256;

    const int r  = q - DIM_I;
    const int i  = r >> 8;
    const int j  = (r >> 4) & 15;
    const int kk = r & 15;
    const float* rs_row = row_s + i * 16;    // rs_row[l]
    const float* cs_row = col_s + j * 16;    // cs_row[m]
    const float* ds_row = dep_s + kk * 16;   // ds_row[n], 16B-aligned rows

    for (int t = threadIdx.x; t < NCHUNK; t += 256) {
        f32x4 v;
        if (t < 5) {
            // k = 4t .. 4t+3, all < 20 (cross block)
            const int k0 = 4 * t;
            v.x = cross[k0 + 0];
            v.y = cross[k0 + 1];
            v.z = cross[k0 + 2];
            v.w = cross[k0 + 3];
        } else {
            const int c0 = 4 * t - DIM_I;        // multiple of 4, >= 0
            const int l  = c0 >> 8;
            const int m  = (c0 >> 4) & 15;
            const int n0 = c0 & 15;              // in {0,4,8,12}
            const float base = rs_row[l] + cs_row[m];
            const f32x4 d = *(const f32x4*)(ds_row + n0);  // 16B aligned
            v = base + d;
        }
        __builtin_nontemporal_store(v, rowp + t);
    }
}

extern "C" void kernel_launch(void* const* d_in, const int* in_sizes, int n_in,
                              void* d_out, int out_size, void* d_ws, size_t ws_size,
                              hipStream_t stream)
{
    const float* enc_cross = (const float*)d_in[0];
    const float* enc_h     = (const float*)d_in[1];
    const float* enc_w     = (const float*)d_in[2];
    const float* enc_d     = (const float*)d_in[3];
    const float* w_cross   = (const float*)d_in[4];
    const float* w_h       = (const float*)d_in[5];
    const float* w_w       = (const float*)d_in[6];
    const float* w_d       = (const float*)d_in[7];

    float* tabs = (float*)d_ws;   // 6304 floats = 25,216 B

    tables_kernel<<<dim3(25), dim3(256), 0, stream>>>(
        enc_cross, enc_h, enc_w, enc_d, w_cross, w_h, w_w, w_d, tabs);

    fill_kernel<<<dim3(DIM_Q, NHEADS), dim3(256), 0, stream>>>(
        tabs, (float*)d_out);
}

// Round 3
// 569.739 us; speedup vs baseline: 1.0410x; 1.0361x over previous
//
#include <hip/hip_runtime.h>

// Problem constants: EMB=64, HEADS=8, TOK=10, CAP=32 (tables 63 rows),
// dim_q=dim_k=4116, dim_i=20, dim_h=dim_w=dim_d=16. S=4096; dim_q=20+4096.
//
// Output (flat fp32): out[h][q][k], h<8, q<4116, k<4116.
//   q <  20            : zeros
//   q >= 20, k <  20   : cross_s[h][k]            * 0.125
//   q >= 20, k >= 20   : (row_s[h][i][l] + col_s[h][j][m] + dep_s[h][kk][n]) * 0.125/3
//     r=q-20: i=r>>8, j=(r>>4)&15, kk=r&15;  c=k-20: l=c>>8, m=(c>>4)&15, n=c&15
//
// ws layout (floats): [0..159]     cross_s (8x20, pre-scaled by 0.125)
//                     [160..2207]  row_s  (8x16x16, pre-scaled by 0.125/3)
//                     [2208..4255] col_s
//                     [4256..6303] dep_s
//
// R3: exact revert to the R0 baseline (best measured, 568.4 µs).
// A/B vs R2 isolates whether nontemporal stores cost ~20 µs or it was
// iteration noise. R1 (16-rows/block restructure) and R2 (nt stores)
// both failed to beat this: the fill is HBM-write-bound and the headline
// is dominated by the harness's 2.17 GB poison fill (~345 µs).

#define EMB 64
#define NHEADS 8
#define DIM_I 20
#define DIM_Q 4116
#define NCHUNK 1029   // DIM_Q/4 float4 per row (row = 16464 B, 16B aligned)

__global__ __launch_bounds__(256) void tables_kernel(
    const float* __restrict__ enc_cross,  // [2][10][64] -> flat [20][64]
    const float* __restrict__ enc_h,      // [63][64]
    const float* __restrict__ enc_w,
    const float* __restrict__ enc_d,
    const float* __restrict__ w_cross,    // [8][64]
    const float* __restrict__ w_h,
    const float* __restrict__ w_w,
    const float* __restrict__ w_d,
    float* __restrict__ tabs)
{
    const int tid = blockIdx.x * blockDim.x + threadIdx.x;
    const int total = NHEADS * DIM_I + 3 * NHEADS * 256;  // 160 + 6144 = 6304
    if (tid >= total) return;

    if (tid < NHEADS * DIM_I) {
        // cross_s[h][n] = dot(w_cross[h], enc_cross_flat[n]) * 0.125
        const int h = tid / DIM_I;
        const int n = tid % DIM_I;
        const float* wv = w_cross + h * EMB;
        const float* ev = enc_cross + n * EMB;
        float acc = 0.f;
        #pragma unroll
        for (int c = 0; c < EMB; ++c) acc += wv[c] * ev[c];
        tabs[tid] = acc * 0.125f;
    } else {
        const int u = tid - NHEADS * DIM_I;
        const int table = u >> 11;          // 0=row, 1=col, 2=dep  (2048 each)
        const int v = u & 2047;
        const int h = v >> 8;
        const int i = (v >> 4) & 15;
        const int l = v & 15;
        // rel index: clip(l - i + 31, 0, 62); with dim 16 it's always in [16,46]
        const int ridx = l - i + 31;
        const float* wv;
        const float* ev;
        if (table == 0)      { wv = w_h + h * EMB; ev = enc_h + ridx * EMB; }
        else if (table == 1) { wv = w_w + h * EMB; ev = enc_w + ridx * EMB; }
        else                 { wv = w_d + h * EMB; ev = enc_d + ridx * EMB; }
        float acc = 0.f;
        #pragma unroll
        for (int c = 0; c < EMB; ++c) acc += wv[c] * ev[c];
        tabs[tid] = acc * (0.125f / 3.0f);
    }
}

__global__ __launch_bounds__(256) void fill_kernel(
    const float* __restrict__ tabs, float* __restrict__ out)
{
    const int q = blockIdx.x;   // 0..4115
    const int h = blockIdx.y;   // 0..7

    float4* rowp = (float4*)(out + ((size_t)h * DIM_Q + q) * DIM_Q);

    if (q < DIM_I) {
        const float4 z = make_float4(0.f, 0.f, 0.f, 0.f);
        for (int t = threadIdx.x; t < NCHUNK; t += 256) rowp[t] = z;
        return;
    }

    const float* cross  = tabs + h * DIM_I;                  // [20]
    const float* row_s  = tabs + 160 + h * 256;              // [16][16]
    const float* col_s  = tabs + 160 + 2048 + h * 256;
    const float* dep_s  = tabs + 160 + 4096 + h * 256;

    const int r  = q - DIM_I;
    const int i  = r >> 8;
    const int j  = (r >> 4) & 15;
    const int kk = r & 15;
    const float* rs_row = row_s + i * 16;    // rs_row[l]
    const float* cs_row = col_s + j * 16;    // cs_row[m]
    const float* ds_row = dep_s + kk * 16;   // ds_row[n]

    for (int t = threadIdx.x; t < NCHUNK; t += 256) {
        float4 v;
        if (t < 5) {
            // k = 4t .. 4t+3, all < 20 (cross block)
            const int k0 = 4 * t;
            v.x = cross[k0 + 0];
            v.y = cross[k0 + 1];
            v.z = cross[k0 + 2];
            v.w = cross[k0 + 3];
        } else {
            const int c0 = 4 * t - DIM_I;        // multiple of 4, >= 0
            const int l  = c0 >> 8;
            const int m  = (c0 >> 4) & 15;
            const int n0 = c0 & 15;              // in {0,4,8,12}
            const float base = rs_row[l] + cs_row[m];
            v.x = base + ds_row[n0 + 0];
            v.y = base + ds_row[n0 + 1];
            v.z = base + ds_row[n0 + 2];
            v.w = base + ds_row[n0 + 3];
        }
        rowp[t] = v;
    }
}

extern "C" void kernel_launch(void* const* d_in, const int* in_sizes, int n_in,
                              void* d_out, int out_size, void* d_ws, size_t ws_size,
                              hipStream_t stream)
{
    const float* enc_cross = (const float*)d_in[0];
    const float* enc_h     = (const float*)d_in[1];
    const float* enc_w     = (const float*)d_in[2];
    const float* enc_d     = (const float*)d_in[3];
    const float* w_cross   = (const float*)d_in[4];
    const float* w_h       = (const float*)d_in[5];
    const float* w_w       = (const float*)d_in[6];
    const float* w_d       = (const float*)d_in[7];

    float* tabs = (float*)d_ws;   // 6304 floats = 25,216 B

    tables_kernel<<<dim3(25), dim3(256), 0, stream>>>(
        enc_cross, enc_h, enc_w, enc_d, w_cross, w_h, w_w, w_d, tabs);

    fill_kernel<<<dim3(DIM_Q, NHEADS), dim3(256), 0, stream>>>(
        tabs, (float*)d_out);
}